// Round 5
// baseline (197.496 us; speedup 1.0000x reference)
//
#include <hip/hip_runtime.h>

#define DIM    256
#define HALF   128
#define F0     10
#define F1     25
#define B0     1024
#define M1     10240    // B0 * F0
#define NNODES 100000
#define NG16   6250     // NNODES / 16
#define PGN_GRID  768   // precompute grid: 3 blocks/CU
#define PGN_ITERS 9     // ceil(NG16 / PGN_GRID)

typedef __attribute__((ext_vector_type(8))) short     bf16x8;  // 8 bf16 = 4 VGPRs
typedef __attribute__((ext_vector_type(4))) float     f32x4;

#define LSTRIDE 264   // LDS A-row stride in bf16 elems (528 B, 16B-aligned)
#define CSTRIDE 136   // LDS C-row stride in bf16 elems (272 B, 16B-aligned)

__device__ __forceinline__ unsigned short f2bf(float x) {
    union { float f; unsigned u; } v; v.f = x;
    unsigned r = v.u + 0x7fffu + ((v.u >> 16) & 1u);   // RNE
    return (unsigned short)(r >> 16);
}
__device__ __forceinline__ float bf2f(unsigned short b) {
    union { unsigned u; float f; } v; v.u = ((unsigned)b) << 16;
    return v.f;
}
// unpack a u32 holding 2 bf16 (lo = even elem, hi = odd elem) to 2 floats
__device__ __forceinline__ void up2(unsigned u, float& lo, float& hi) {
    union { unsigned x; float f; } a, b;
    a.x = u << 16; b.x = u & 0xffff0000u;
    lo = a.f; hi = b.f;
}
__device__ __forceinline__ void acc2(float& a, float& b, unsigned u) {
    float lo, hi; up2(u, lo, hi); a += lo; b += hi;
}
__device__ __forceinline__ unsigned pk(float lo, float hi) {
    return (unsigned)f2bf(lo) | ((unsigned)f2bf(hi) << 16);
}

// ---------- Prep: W0_{self,neigh} -> bf16 B-fragments in frag-linear order.
// B-frag for (mat, tile t, kstep kk), lane = q*16+n, j=0..7 : W[kk*32+q*8+j][t*16+n]
// stored at bfrag[((mat*64 + t*8+kk)*64 + lane)*8 + j].  mat0=W0s, mat1=W0n.
__global__ __launch_bounds__(64) void prep_w(
    const float* __restrict__ Ws,
    const float* __restrict__ Wn,
    unsigned short* __restrict__ bfrag)
{
    const int bx   = blockIdx.x;       // [0,128)
    const int mat  = bx >> 6;
    const int f    = bx & 63;          // t*8+kk
    const int kk   = f & 7;
    const int t    = f >> 3;
    const int lane = threadIdx.x;
    const int n    = lane & 15, q = lane >> 4;
    const float* W = mat ? Wn : Ws;

    __align__(16) unsigned short tmp[8];
    #pragma unroll
    for (int j = 0; j < 8; ++j)
        tmp[j] = f2bf(W[(kk * 32 + q * 8 + j) * HALF + t * 16 + n]);
    *(uint4*)(bfrag + ((size_t)(mat * 64 + f) * 64 + lane) * 8) = *(const uint4*)tmp;
}

// ---------- Precompute Gn = bf16(feat) @ W0_neigh only, stored bf16 [node][128].
// (Self half is NOT precomputed: only ~11K of 100K rows ever need it; the gather
// kernel computes it directly.)  Gn writes are coalesced via an LDS transpose tile
// (one dwordx4 per thread) instead of scattered 2-B stores.
__global__ __launch_bounds__(256, 3) void precompute_gn(
    const float* __restrict__ feat,
    const unsigned short* __restrict__ bfrag,
    unsigned short* __restrict__ Gn)
{
    __shared__ __align__(16) unsigned short ash[16][LSTRIDE];   // 8.4 KB A tile
    __shared__ __align__(16) unsigned short csh[16][CSTRIDE];   // 4.3 KB C tile

    const int tid  = threadIdx.x;                                // 256
    const int wv   = __builtin_amdgcn_readfirstlane(tid >> 6);   // 0..3
    const int lane = tid & 63;
    const int m    = lane & 15;
    const int q    = lane >> 4;

    // one-time: this wave's W0n fragments (tiles 2wv, 2wv+1) -> registers (64 VGPR)
    bf16x8 breg[2][8];
    #pragma unroll
    for (int i = 0; i < 2; ++i)
        #pragma unroll
        for (int kk = 0; kk < 8; ++kk)
            breg[i][kk] = *(const bf16x8*)(bfrag +
                ((size_t)(64 + (wv * 2 + i) * 8 + kk) * 64 + lane) * 8);

    // A staging: thread t owns row t>>4, cols (t&15)*16 .. +15
    const int row16 = tid >> 4;
    const int c0    = (tid & 15) * 16;

    float4 p1[4];
    auto LOADG = [&](int gg) {
        const int cg = gg < NG16 ? gg : NG16 - 1;      // clamp (data unused when OOB)
        const float* src = feat + ((size_t)cg * 16 + row16) * DIM + c0;
        p1[0] = *(const float4*)(src);
        p1[1] = *(const float4*)(src + 4);
        p1[2] = *(const float4*)(src + 8);
        p1[3] = *(const float4*)(src + 12);
    };

    int g = blockIdx.x;
    LOADG(g);

    for (int it = 0; it < PGN_ITERS; ++it, g += PGN_GRID) {
        // stage A (consumes p1 loaded last iteration / prologue)
        {
            __align__(16) unsigned short tmp[16];
            #pragma unroll
            for (int k = 0; k < 4; ++k) {
                tmp[k * 4 + 0] = f2bf(p1[k].x);
                tmp[k * 4 + 1] = f2bf(p1[k].y);
                tmp[k * 4 + 2] = f2bf(p1[k].z);
                tmp[k * 4 + 3] = f2bf(p1[k].w);
            }
            *(uint4*)(&ash[row16][c0])     = *(const uint4*)(tmp);
            *(uint4*)(&ash[row16][c0 + 8]) = *(const uint4*)(tmp + 8);
        }
        __syncthreads();            // ash visible; prev iter's csh reads also done

        LOADG(g + PGN_GRID);        // prefetch next group (covered by MFMA+stores)

        f32x4 acc[2] = { {0.f,0.f,0.f,0.f}, {0.f,0.f,0.f,0.f} };
        #pragma unroll
        for (int kk = 0; kk < 8; ++kk) {
            const bf16x8 af = *(const bf16x8*)(&ash[m][kk * 32 + q * 8]);
            #pragma unroll
            for (int i = 0; i < 2; ++i)
                acc[i] = __builtin_amdgcn_mfma_f32_16x16x32_bf16(af, breg[i][kk], acc[i], 0, 0, 0);
        }

        // C -> LDS transpose (C/D layout: col = lane&15 within tile, row = q*4+reg)
        #pragma unroll
        for (int i = 0; i < 2; ++i) {
            const int col = (wv * 2 + i) * 16 + m;
            #pragma unroll
            for (int reg = 0; reg < 4; ++reg)
                csh[q * 4 + reg][col] = f2bf(acc[i][reg]);
        }
        __syncthreads();            // csh visible; ash MFMA reads done

        if (g < NG16) {             // coalesced: 16 B/thread, 4 KB contiguous/block
            const uint4 vv = *(const uint4*)(&csh[row16][(tid & 15) * 8]);
            *(uint4*)(Gn + (size_t)(g * 16 + row16) * HALF + (tid & 15) * 8) = vv;
        }
    }
}

// ---------- Fused layer-0: per 16-row block,
//   self half  = relu(bf16(feat[self]) @ W0s)   (MFMA, W0s frags in registers)
//   neigh half = relu(mean_j Gn[nb[r,j]])       (gather + mean)
template<int NF, bool FP32OUT>
__device__ __forceinline__ void gather_hop(
    const float* __restrict__ feat,
    const unsigned short* __restrict__ Gn,
    const unsigned short* __restrict__ bfrag,
    const int* __restrict__ selfIdx,
    const int* __restrict__ neighIdx,
    int rowbase,
    int* s_self, int* s_nb,
    unsigned short (*ash)[LSTRIDE],
    float*          __restrict__ dstF,   // hop0: n0 fp32 (in d_out)
    unsigned short* __restrict__ dstB)   // hop1: n1 bf16 (in ws)
{
    const int tid  = threadIdx.x;   // 256
    const int wv   = __builtin_amdgcn_readfirstlane(tid >> 6);   // 0..3
    const int lane = tid & 63;
    const int m    = lane & 15;
    const int q    = lane >> 4;

    // W0s fragments for this wave's tiles (2wv, 2wv+1) -> registers (L2-hot)
    bf16x8 breg[2][8];
    #pragma unroll
    for (int i = 0; i < 2; ++i)
        #pragma unroll
        for (int kk = 0; kk < 8; ++kk)
            breg[i][kk] = *(const bf16x8*)(bfrag +
                ((size_t)((wv * 2 + i) * 8 + kk) * 64 + lane) * 8);

    // stage the block's indices into LDS
    for (int t = tid; t < 16 * NF; t += 256) s_nb[t] = neighIdx[rowbase * NF + t];
    if (tid < 16) s_self[tid] = selfIdx[rowbase + tid];
    __syncthreads();

    const int slot = tid >> 4;     // row within block
    const int sub  = tid & 15;     // 16B/64B chunk within row
    const int row  = rowbase + slot;

    // issue self-feature loads first (1 KB coalesced per row: 16 thr x 64 B)
    const int si = s_self[slot];
    const float* fsrc = feat + (size_t)si * DIM + sub * 16;
    float4 pf0 = *(const float4*)(fsrc);
    float4 pf1 = *(const float4*)(fsrc + 4);
    float4 pf2 = *(const float4*)(fsrc + 8);
    float4 pf3 = *(const float4*)(fsrc + 12);

    // ---- neighbor half: mean over NF gathered Gn rows (256 B each)
    {
        float a[8] = {0.f,0.f,0.f,0.f,0.f,0.f,0.f,0.f};
        #pragma unroll 5
        for (int j = 0; j < NF; ++j) {
            const int gi = s_nb[slot * NF + j];
            const uint4 v = *(const uint4*)(Gn + (size_t)gi * HALF + sub * 8);
            acc2(a[0], a[1], v.x); acc2(a[2], a[3], v.y);
            acc2(a[4], a[5], v.z); acc2(a[6], a[7], v.w);
        }
        const float sc = 1.0f / (float)NF;
        #pragma unroll
        for (int k = 0; k < 8; ++k) a[k] = fmaxf(a[k] * sc, 0.f);
        if (FP32OUT) {
            float4 o0 = { a[0], a[1], a[2], a[3] };
            float4 o1 = { a[4], a[5], a[6], a[7] };
            *(float4*)(dstF + (size_t)row * DIM + HALF + sub * 8)     = o0;
            *(float4*)(dstF + (size_t)row * DIM + HALF + sub * 8 + 4) = o1;
        } else {
            uint4 o;
            o.x = pk(a[0], a[1]); o.y = pk(a[2], a[3]);
            o.z = pk(a[4], a[5]); o.w = pk(a[6], a[7]);
            *(uint4*)(dstB + (size_t)row * DIM + HALF + sub * 8) = o;
        }
    }

    // stage self features (bf16) into LDS
    {
        __align__(16) unsigned short tmp[16];
        const float4 pf[4] = { pf0, pf1, pf2, pf3 };
        #pragma unroll
        for (int k = 0; k < 4; ++k) {
            tmp[k * 4 + 0] = f2bf(pf[k].x);
            tmp[k * 4 + 1] = f2bf(pf[k].y);
            tmp[k * 4 + 2] = f2bf(pf[k].z);
            tmp[k * 4 + 3] = f2bf(pf[k].w);
        }
        *(uint4*)(&ash[slot][sub * 16])     = *(const uint4*)(tmp);
        *(uint4*)(&ash[slot][sub * 16 + 8]) = *(const uint4*)(tmp + 8);
    }
    __syncthreads();

    // ---- self half: MFMA 16x256 @ 256x128 (W0s), relu, store
    f32x4 acc[2] = { {0.f,0.f,0.f,0.f}, {0.f,0.f,0.f,0.f} };
    #pragma unroll
    for (int kk = 0; kk < 8; ++kk) {
        const bf16x8 af = *(const bf16x8*)(&ash[m][kk * 32 + q * 8]);
        #pragma unroll
        for (int i = 0; i < 2; ++i)
            acc[i] = __builtin_amdgcn_mfma_f32_16x16x32_bf16(af, breg[i][kk], acc[i], 0, 0, 0);
    }
    #pragma unroll
    for (int i = 0; i < 2; ++i) {
        const int col = (wv * 2 + i) * 16 + m;
        #pragma unroll
        for (int reg = 0; reg < 4; ++reg) {
            const float v = fmaxf(acc[i][reg], 0.f);
            const int   r = rowbase + q * 4 + reg;
            if (FP32OUT) dstF[(size_t)r * DIM + col] = v;
            else         dstB[(size_t)r * DIM + col] = f2bf(v);
        }
    }
}

__global__ __launch_bounds__(256, 2) void sage_gather(
    const float* __restrict__ feat,
    const unsigned short* __restrict__ Gn,
    const unsigned short* __restrict__ bfrag,
    const int* __restrict__ sn0,
    const int* __restrict__ sn1,
    const int* __restrict__ sn2,
    float*          __restrict__ n0,
    unsigned short* __restrict__ n1)
{
    __shared__ __align__(16) unsigned short ash[16][LSTRIDE];
    __shared__ int s_self[16];
    __shared__ int s_nb[16 * F1];

    int gb = blockIdx.x;
    if (gb < B0 / 16) {
        gather_hop<F0, true >(feat, Gn, bfrag, sn0, sn1, gb * 16, s_self, s_nb, ash, n0, nullptr);
    } else {
        gb -= B0 / 16;
        gather_hop<F1, false>(feat, Gn, bfrag, sn1, sn2, gb * 16, s_self, s_nb, ash, nullptr, n1);
    }
}

// ---------- Final layer: out = concat(n0 @ W1s, mean10(n1) @ W1n), fp32 VALU.
#define PAD 260
#define R2  4

__global__ __launch_bounds__(256) void sage_final(
    const unsigned short* __restrict__ n1,
    const float* __restrict__ W1s,
    const float* __restrict__ W1n,
    float*       out)              // aliases n0 input — no restrict
{
    __shared__ float sh_n0 [R2][PAD];
    __shared__ float sh_agg[R2][PAD];

    const int tid     = threadIdx.x;
    const int rowbase = blockIdx.x * R2;
    const int wave    = tid >> 6;
    const int lane    = tid & 63;

    {
        const int r = wave;
        *(float4*)(&sh_n0[r][lane * 4]) =
            *(const float4*)(out + (size_t)(rowbase + r) * DIM + lane * 4);

        const unsigned short* base = n1 + ((size_t)(rowbase + r) * F0) * DIM + lane * 4;
        float4 a = make_float4(0.f, 0.f, 0.f, 0.f);
        #pragma unroll
        for (int j = 0; j < F0; ++j) {
            const uint2 p = *(const uint2*)(base + (size_t)j * DIM);
            a.x += bf2f((unsigned short)(p.x & 0xffff));
            a.y += bf2f((unsigned short)(p.x >> 16));
            a.z += bf2f((unsigned short)(p.y & 0xffff));
            a.w += bf2f((unsigned short)(p.y >> 16));
        }
        const float sc = 1.0f / (float)F0;
        a.x *= sc; a.y *= sc; a.z *= sc; a.w *= sc;
        *(float4*)(&sh_agg[r][lane * 4]) = a;
    }
    __syncthreads();

    const int  u     = tid & 127;
    const int  c0    = u * 2;
    const int  rb    = (tid >> 7) * 2;
    const bool neigh = (c0 >= HALF);
    const float* __restrict__ W = neigh ? W1n : W1s;
    const int  col   = neigh ? (c0 - HALF) : c0;
    const float (*src)[PAD] = neigh ? sh_agg : sh_n0;

    float a0[2] = {0.f, 0.f}, a1[2] = {0.f, 0.f};
    for (int d = 0; d < DIM; d += 4) {
        const float2 w0 = *(const float2*)(W + (d + 0) * HALF + col);
        const float2 w1 = *(const float2*)(W + (d + 1) * HALF + col);
        const float2 w2 = *(const float2*)(W + (d + 2) * HALF + col);
        const float2 w3 = *(const float2*)(W + (d + 3) * HALF + col);
        #pragma unroll
        for (int r = 0; r < 2; ++r) {
            const float4 hh = *(const float4*)(&src[rb + r][d]);
            a0[r] += hh.x * w0.x + hh.y * w1.x + hh.z * w2.x + hh.w * w3.x;
            a1[r] += hh.x * w0.y + hh.y * w1.y + hh.z * w2.y + hh.w * w3.y;
        }
    }

    #pragma unroll
    for (int r = 0; r < 2; ++r) {
        float2 o;
        o.x = a0[r];
        o.y = a1[r];
        *(float2*)(out + (size_t)(rowbase + rb + r) * DIM + c0) = o;
    }
}

extern "C" void kernel_launch(void* const* d_in, const int* in_sizes, int n_in,
                              void* d_out, int out_size, void* d_ws, size_t ws_size,
                              hipStream_t stream) {
    (void)in_sizes; (void)n_in; (void)out_size; (void)ws_size;
    const float* feat = (const float*)d_in[0];
    const int*   sn0  = (const int*)  d_in[1];
    const int*   sn1  = (const int*)  d_in[2];
    const int*   sn2  = (const int*)  d_in[3];
    const float* W0s  = (const float*)d_in[4];
    const float* W0n  = (const float*)d_in[5];
    const float* W1s  = (const float*)d_in[6];
    const float* W1n  = (const float*)d_in[7];
    float* out = (float*)d_out;

    // ws layout (total ~31 MB):
    //   [0, 5,242,880)               n1 bf16  (10240 x 256 x 2)
    //   [5,242,880, 5,373,952)       W0 B-fragments (128 KB, 16B-aligned)
    //   [5,373,952, +25,600,000)     Gn bf16  (100000 x 128 x 2)
    unsigned short* n1    = (unsigned short*)d_ws;
    unsigned short* bfrag = (unsigned short*)((char*)d_ws + (size_t)M1 * DIM * 2);
    unsigned short* Gn    = (unsigned short*)((char*)d_ws + (size_t)M1 * DIM * 2 + 131072);

    prep_w<<<128, 64, 0, stream>>>(W0s, W0n, bfrag);
    precompute_gn<<<PGN_GRID, 256, 0, stream>>>(feat, bfrag, Gn);
    // n0 (1024x256 fp32) staged in d_out, then overwritten in-place by sage_final.
    sage_gather<<<(B0 + M1) / 16, 256, 0, stream>>>(feat, Gn, bfrag, sn0, sn1, sn2, out, n1);
    sage_final<<<B0 / R2, 256, 0, stream>>>(n1, W1s, W1n, out);
}

// Round 6
// 192.588 us; speedup vs baseline: 1.0255x; 1.0255x over previous
//
#include <hip/hip_runtime.h>

#define DIM    256
#define HALF   128
#define F0     10
#define F1     25
#define B0     1024
#define M1     10240    // B0 * F0
#define NNODES 100000
#define NG16   6250     // NNODES / 16
#define PGN_GRID  768   // Gn-stream blocks: 3 blocks/CU
#define PGN_ITERS 9     // ceil(NG16 / PGN_GRID)
#define NSELF     704   // self blocks: (B0 + M1) / 16

typedef __attribute__((ext_vector_type(8))) short     bf16x8;  // 8 bf16 = 4 VGPRs
typedef __attribute__((ext_vector_type(4))) float     f32x4;

#define LSTRIDE 264   // LDS A-row stride in bf16 elems (528 B, 16B-aligned)
#define CSTRIDE 136   // LDS C-row stride in bf16 elems (272 B, 16B-aligned)

__device__ __forceinline__ unsigned short f2bf(float x) {
    union { float f; unsigned u; } v; v.f = x;
    unsigned r = v.u + 0x7fffu + ((v.u >> 16) & 1u);   // RNE
    return (unsigned short)(r >> 16);
}
__device__ __forceinline__ float bf2f(unsigned short b) {
    union { unsigned u; float f; } v; v.u = ((unsigned)b) << 16;
    return v.f;
}
// unpack a u32 holding 2 bf16 (lo = even elem, hi = odd elem) to 2 floats
__device__ __forceinline__ void up2(unsigned u, float& lo, float& hi) {
    union { unsigned x; float f; } a, b;
    a.x = u << 16; b.x = u & 0xffff0000u;
    lo = a.f; hi = b.f;
}
__device__ __forceinline__ void acc2(float& a, float& b, unsigned u) {
    float lo, hi; up2(u, lo, hi); a += lo; b += hi;
}
__device__ __forceinline__ unsigned pk(float lo, float hi) {
    return (unsigned)f2bf(lo) | ((unsigned)f2bf(hi) << 16);
}

// ---------- Prep: W0_{self,neigh} -> bf16 B-fragments in frag-linear order.
// B-frag for (mat, tile t, kstep kk), lane = q*16+n, j=0..7 : W[kk*32+q*8+j][t*16+n]
// stored at bfrag[((mat*64 + t*8+kk)*64 + lane)*8 + j].  mat0=W0s, mat1=W0n.
__global__ __launch_bounds__(64) void prep_w(
    const float* __restrict__ Ws,
    const float* __restrict__ Wn,
    unsigned short* __restrict__ bfrag)
{
    const int bx   = blockIdx.x;       // [0,128)
    const int mat  = bx >> 6;
    const int f    = bx & 63;          // t*8+kk
    const int kk   = f & 7;
    const int t    = f >> 3;
    const int lane = threadIdx.x;
    const int n    = lane & 15, q = lane >> 4;
    const float* W = mat ? Wn : Ws;

    __align__(16) unsigned short tmp[8];
    #pragma unroll
    for (int j = 0; j < 8; ++j)
        tmp[j] = f2bf(W[(kk * 32 + q * 8 + j) * HALF + t * 16 + n]);
    *(uint4*)(bfrag + ((size_t)(mat * 64 + f) * 64 + lane) * 8) = *(const uint4*)tmp;
}

// ---------- Merged precompute, role-split grid (one dispatch so the small self-GEMM
// work overlaps the BW-bound Gn stream instead of serializing behind it):
//   blocks [0, PGN_GRID):        Gn = bf16(feat) @ W0n, bf16 [node][128], coalesced
//                                stores via LDS transpose tile.
//   blocks [PGN_GRID, +NSELF):   self halves: relu(bf16(feat[self]) @ W0s) ->
//                                n0[:, :128] fp32 (hop0) / n1[:, :128] bf16 (hop1).
__global__ __launch_bounds__(256, 3) void precompute_all(
    const float* __restrict__ feat,
    const unsigned short* __restrict__ bfrag,
    unsigned short* __restrict__ Gn,
    const int* __restrict__ sn0,
    const int* __restrict__ sn1,
    float*          __restrict__ n0,
    unsigned short* __restrict__ n1)
{
    __shared__ __align__(16) unsigned short ash[16][LSTRIDE];   // 8.4 KB A tile
    __shared__ __align__(16) unsigned short csh[16][CSTRIDE];   // 4.3 KB C tile

    const int tid  = threadIdx.x;                                // 256
    const int wv   = __builtin_amdgcn_readfirstlane(tid >> 6);   // 0..3
    const int lane = tid & 63;
    const int m    = lane & 15;
    const int q    = lane >> 4;
    const int row16 = tid >> 4;      // row owned for staging/stores
    const int sub   = tid & 15;      // 16-elem chunk within row
    const int c0    = sub * 16;

    if (blockIdx.x < PGN_GRID) {
        // ================= role 0: Gn stream =================
        // W0n fragments (tiles 2wv, 2wv+1) -> registers (64 VGPR)
        bf16x8 breg[2][8];
        #pragma unroll
        for (int i = 0; i < 2; ++i)
            #pragma unroll
            for (int kk = 0; kk < 8; ++kk)
                breg[i][kk] = *(const bf16x8*)(bfrag +
                    ((size_t)(64 + (wv * 2 + i) * 8 + kk) * 64 + lane) * 8);

        float4 p1[4];
        auto LOADG = [&](int gg) {
            const int cg = gg < NG16 ? gg : NG16 - 1;    // clamp (data unused when OOB)
            const float* src = feat + ((size_t)cg * 16 + row16) * DIM + c0;
            p1[0] = *(const float4*)(src);
            p1[1] = *(const float4*)(src + 4);
            p1[2] = *(const float4*)(src + 8);
            p1[3] = *(const float4*)(src + 12);
        };

        int g = blockIdx.x;
        LOADG(g);

        for (int it = 0; it < PGN_ITERS; ++it, g += PGN_GRID) {
            {   // stage A (consumes p1 loaded last iteration / prologue)
                __align__(16) unsigned short tmp[16];
                #pragma unroll
                for (int k = 0; k < 4; ++k) {
                    tmp[k * 4 + 0] = f2bf(p1[k].x);
                    tmp[k * 4 + 1] = f2bf(p1[k].y);
                    tmp[k * 4 + 2] = f2bf(p1[k].z);
                    tmp[k * 4 + 3] = f2bf(p1[k].w);
                }
                *(uint4*)(&ash[row16][c0])     = *(const uint4*)(tmp);
                *(uint4*)(&ash[row16][c0 + 8]) = *(const uint4*)(tmp + 8);
            }
            __syncthreads();        // ash visible; prev iter's csh reads also done

            LOADG(g + PGN_GRID);    // prefetch next group (covered by MFMA+stores)

            f32x4 acc[2] = { {0.f,0.f,0.f,0.f}, {0.f,0.f,0.f,0.f} };
            #pragma unroll
            for (int kk = 0; kk < 8; ++kk) {
                const bf16x8 af = *(const bf16x8*)(&ash[m][kk * 32 + q * 8]);
                #pragma unroll
                for (int i = 0; i < 2; ++i)
                    acc[i] = __builtin_amdgcn_mfma_f32_16x16x32_bf16(af, breg[i][kk], acc[i], 0, 0, 0);
            }

            // C -> LDS transpose (C/D layout: col = lane&15 in tile, row = q*4+reg)
            #pragma unroll
            for (int i = 0; i < 2; ++i) {
                const int col = (wv * 2 + i) * 16 + m;
                #pragma unroll
                for (int reg = 0; reg < 4; ++reg)
                    csh[q * 4 + reg][col] = f2bf(acc[i][reg]);
            }
            __syncthreads();        // csh visible; ash MFMA reads done

            if (g < NG16) {         // coalesced: 16 B/thread, 4 KB contiguous/block
                const uint4 vv = *(const uint4*)(&csh[row16][sub * 8]);
                *(uint4*)(Gn + (size_t)(g * 16 + row16) * HALF + sub * 8) = vv;
            }
        }
    } else {
        // ================= role 1/2: self halves =================
        const int sb      = blockIdx.x - PGN_GRID;     // 0..703
        const bool hop0   = sb < (B0 / 16);
        const int rowbase = (hop0 ? sb : sb - B0 / 16) * 16;
        const int* selfIdx = hop0 ? sn0 : sn1;

        // index + self-feature loads (1 KB coalesced per row: 16 thr x 64 B)
        const int si = selfIdx[rowbase + row16];
        const float* fsrc = feat + (size_t)si * DIM + c0;
        const float4 pf0 = *(const float4*)(fsrc);
        const float4 pf1 = *(const float4*)(fsrc + 4);
        const float4 pf2 = *(const float4*)(fsrc + 8);
        const float4 pf3 = *(const float4*)(fsrc + 12);

        // W0s fragments (tiles 2wv, 2wv+1) -> registers (L2-hot)
        bf16x8 breg[2][8];
        #pragma unroll
        for (int i = 0; i < 2; ++i)
            #pragma unroll
            for (int kk = 0; kk < 8; ++kk)
                breg[i][kk] = *(const bf16x8*)(bfrag +
                    ((size_t)((wv * 2 + i) * 8 + kk) * 64 + lane) * 8);

        {   // stage self features (bf16) into LDS
            __align__(16) unsigned short tmp[16];
            const float4 pf[4] = { pf0, pf1, pf2, pf3 };
            #pragma unroll
            for (int k = 0; k < 4; ++k) {
                tmp[k * 4 + 0] = f2bf(pf[k].x);
                tmp[k * 4 + 1] = f2bf(pf[k].y);
                tmp[k * 4 + 2] = f2bf(pf[k].z);
                tmp[k * 4 + 3] = f2bf(pf[k].w);
            }
            *(uint4*)(&ash[row16][c0])     = *(const uint4*)(tmp);
            *(uint4*)(&ash[row16][c0 + 8]) = *(const uint4*)(tmp + 8);
        }
        __syncthreads();

        f32x4 acc[2] = { {0.f,0.f,0.f,0.f}, {0.f,0.f,0.f,0.f} };
        #pragma unroll
        for (int kk = 0; kk < 8; ++kk) {
            const bf16x8 af = *(const bf16x8*)(&ash[m][kk * 32 + q * 8]);
            #pragma unroll
            for (int i = 0; i < 2; ++i)
                acc[i] = __builtin_amdgcn_mfma_f32_16x16x32_bf16(af, breg[i][kk], acc[i], 0, 0, 0);
        }
        #pragma unroll
        for (int i = 0; i < 2; ++i) {
            const int col = (wv * 2 + i) * 16 + m;
            #pragma unroll
            for (int reg = 0; reg < 4; ++reg) {
                const float v = fmaxf(acc[i][reg], 0.f);
                const int   r = rowbase + q * 4 + reg;
                if (hop0) n0[(size_t)r * DIM + col] = v;
                else      n1[(size_t)r * DIM + col] = f2bf(v);
            }
        }
    }
}

// ---------- Neighbor-only layer-0: per row r, cols [128,256) = relu(mean_j Gn[nb[r,j]]).
template<int NF, bool FP32OUT>
__device__ __forceinline__ void neigh_hop(
    const unsigned short* __restrict__ Gn,
    const int* __restrict__ neighIdx,
    int rowbase,
    int* s_nb,
    float*          __restrict__ dstF,   // hop0: n0 fp32 (in d_out)
    unsigned short* __restrict__ dstB)   // hop1: n1 bf16 (in ws)
{
    const int tid = threadIdx.x;   // 256

    // stage the block's indices into LDS (decouples idx->data dependent chain)
    for (int t = tid; t < 16 * NF; t += 256) s_nb[t] = neighIdx[rowbase * NF + t];
    __syncthreads();

    const int slot = tid >> 4;     // row within block
    const int sub  = tid & 15;     // 16 B chunk within 256 B row
    const int row  = rowbase + slot;

    float a[8] = {0.f,0.f,0.f,0.f,0.f,0.f,0.f,0.f};
    #pragma unroll 5
    for (int j = 0; j < NF; ++j) {
        const int gi = s_nb[slot * NF + j];
        const uint4 v = *(const uint4*)(Gn + (size_t)gi * HALF + sub * 8);
        acc2(a[0], a[1], v.x); acc2(a[2], a[3], v.y);
        acc2(a[4], a[5], v.z); acc2(a[6], a[7], v.w);
    }
    const float sc = 1.0f / (float)NF;
    #pragma unroll
    for (int k = 0; k < 8; ++k) a[k] = fmaxf(a[k] * sc, 0.f);
    if (FP32OUT) {
        float4 o0 = { a[0], a[1], a[2], a[3] };
        float4 o1 = { a[4], a[5], a[6], a[7] };
        *(float4*)(dstF + (size_t)row * DIM + HALF + sub * 8)     = o0;
        *(float4*)(dstF + (size_t)row * DIM + HALF + sub * 8 + 4) = o1;
    } else {
        uint4 o;
        o.x = pk(a[0], a[1]); o.y = pk(a[2], a[3]);
        o.z = pk(a[4], a[5]); o.w = pk(a[6], a[7]);
        *(uint4*)(dstB + (size_t)row * DIM + HALF + sub * 8) = o;
    }
}

__global__ __launch_bounds__(256) void sage_gather(
    const unsigned short* __restrict__ Gn,
    const int* __restrict__ sn1,
    const int* __restrict__ sn2,
    float*          __restrict__ n0,
    unsigned short* __restrict__ n1)
{
    __shared__ int s_nb[16 * F1];

    int gb = blockIdx.x;
    if (gb < B0 / 16) {
        neigh_hop<F0, true >(Gn, sn1, gb * 16, s_nb, n0, nullptr);
    } else {
        gb -= B0 / 16;
        neigh_hop<F1, false>(Gn, sn2, gb * 16, s_nb, nullptr, n1);
    }
}

// ---------- Final layer: out = concat(n0 @ W1s, mean10(n1) @ W1n), fp32 VALU.
#define PAD 260
#define R2  4

__global__ __launch_bounds__(256) void sage_final(
    const unsigned short* __restrict__ n1,
    const float* __restrict__ W1s,
    const float* __restrict__ W1n,
    float*       out)              // aliases n0 input — no restrict
{
    __shared__ float sh_n0 [R2][PAD];
    __shared__ float sh_agg[R2][PAD];

    const int tid     = threadIdx.x;
    const int rowbase = blockIdx.x * R2;
    const int wave    = tid >> 6;
    const int lane    = tid & 63;

    {
        const int r = wave;
        *(float4*)(&sh_n0[r][lane * 4]) =
            *(const float4*)(out + (size_t)(rowbase + r) * DIM + lane * 4);

        const unsigned short* base = n1 + ((size_t)(rowbase + r) * F0) * DIM + lane * 4;
        float4 a = make_float4(0.f, 0.f, 0.f, 0.f);
        #pragma unroll
        for (int j = 0; j < F0; ++j) {
            const uint2 p = *(const uint2*)(base + (size_t)j * DIM);
            a.x += bf2f((unsigned short)(p.x & 0xffff));
            a.y += bf2f((unsigned short)(p.x >> 16));
            a.z += bf2f((unsigned short)(p.y & 0xffff));
            a.w += bf2f((unsigned short)(p.y >> 16));
        }
        const float sc = 1.0f / (float)F0;
        a.x *= sc; a.y *= sc; a.z *= sc; a.w *= sc;
        *(float4*)(&sh_agg[r][lane * 4]) = a;
    }
    __syncthreads();

    const int  u     = tid & 127;
    const int  c0    = u * 2;
    const int  rb    = (tid >> 7) * 2;
    const bool neigh = (c0 >= HALF);
    const float* __restrict__ W = neigh ? W1n : W1s;
    const int  col   = neigh ? (c0 - HALF) : c0;
    const float (*src)[PAD] = neigh ? sh_agg : sh_n0;

    float a0[2] = {0.f, 0.f}, a1[2] = {0.f, 0.f};
    for (int d = 0; d < DIM; d += 4) {
        const float2 w0 = *(const float2*)(W + (d + 0) * HALF + col);
        const float2 w1 = *(const float2*)(W + (d + 1) * HALF + col);
        const float2 w2 = *(const float2*)(W + (d + 2) * HALF + col);
        const float2 w3 = *(const float2*)(W + (d + 3) * HALF + col);
        #pragma unroll
        for (int r = 0; r < 2; ++r) {
            const float4 hh = *(const float4*)(&src[rb + r][d]);
            a0[r] += hh.x * w0.x + hh.y * w1.x + hh.z * w2.x + hh.w * w3.x;
            a1[r] += hh.x * w0.y + hh.y * w1.y + hh.z * w2.y + hh.w * w3.y;
        }
    }

    #pragma unroll
    for (int r = 0; r < 2; ++r) {
        float2 o;
        o.x = a0[r];
        o.y = a1[r];
        *(float2*)(out + (size_t)(rowbase + rb + r) * DIM + c0) = o;
    }
}

extern "C" void kernel_launch(void* const* d_in, const int* in_sizes, int n_in,
                              void* d_out, int out_size, void* d_ws, size_t ws_size,
                              hipStream_t stream) {
    (void)in_sizes; (void)n_in; (void)out_size; (void)ws_size;
    const float* feat = (const float*)d_in[0];
    const int*   sn0  = (const int*)  d_in[1];
    const int*   sn1  = (const int*)  d_in[2];
    const int*   sn2  = (const int*)  d_in[3];
    const float* W0s  = (const float*)d_in[4];
    const float* W0n  = (const float*)d_in[5];
    const float* W1s  = (const float*)d_in[6];
    const float* W1n  = (const float*)d_in[7];
    float* out = (float*)d_out;

    // ws layout (total ~31 MB):
    //   [0, 5,242,880)               n1 bf16  (10240 x 256 x 2)
    //   [5,242,880, 5,373,952)       W0 B-fragments (128 KB, 16B-aligned)
    //   [5,373,952, +25,600,000)     Gn bf16  (100000 x 128 x 2)
    unsigned short* n1    = (unsigned short*)d_ws;
    unsigned short* bfrag = (unsigned short*)((char*)d_ws + (size_t)M1 * DIM * 2);
    unsigned short* Gn    = (unsigned short*)((char*)d_ws + (size_t)M1 * DIM * 2 + 131072);

    prep_w<<<128, 64, 0, stream>>>(W0s, W0n, bfrag);
    // one dispatch: Gn stream (768 blocks) + self halves (704 blocks) overlap.
    precompute_all<<<PGN_GRID + NSELF, 256, 0, stream>>>(feat, bfrag, Gn, sn0, sn1, out, n1);
    // neighbor-only gather (thin): writes n0/n1 cols [128,256).
    sage_gather<<<(B0 + M1) / 16, 256, 0, stream>>>(Gn, sn1, sn2, out, n1);
    sage_final<<<B0 / R2, 256, 0, stream>>>(n1, W1s, W1n, out);
}